// Round 4
// baseline (734.714 us; speedup 1.0000x reference)
//
#include <hip/hip_runtime.h>

// GroupedQueryAttention: B=1, S=2048, D_IN=D_OUT=4096, NH=32, NKV=8, HD=128, causal.
// Pipeline: cast->bf16, fused QKV GEMM (MFMA, swizzled LDS), RoPE (vec),
//           K/V fragment-order pack, barrier-free COALESCED flash attention, out GEMM.

typedef __bf16 bf16;
typedef __bf16 bf16x4 __attribute__((ext_vector_type(4)));
typedef __bf16 bf16x8 __attribute__((ext_vector_type(8)));
typedef float  f32x4  __attribute__((ext_vector_type(4)));

#define S_LEN   2048
#define DMODEL  4096
#define QKV_N   6144      // 4096 Q + 1024 K + 1024 V
#define K_OFF   4096
#define V_OFF   5120
#define HD      128
#define ATT_SCALE 0.08838834764831845f  // 1/sqrt(128)

// async global->LDS, 16B per lane; LDS dest is wave-uniform base + lane*16
__device__ __forceinline__ void gload16(const bf16* g, bf16* l) {
    __builtin_amdgcn_global_load_lds(
        (__attribute__((address_space(1))) void*)(g),
        (__attribute__((address_space(3))) void*)(l),
        16, 0, 0);
}

// ---------------- cast fp32 -> bf16, float4 vectorized ----------------
__global__ __launch_bounds__(256) void cast_f32_bf16(const float* __restrict__ in,
                                                     bf16* __restrict__ out, int n4) {
    int i = blockIdx.x * 256 + threadIdx.x;
    if (i >= n4) return;
    float4 v = reinterpret_cast<const float4*>(in)[i];
    bf16x4 o;
    o[0] = (bf16)v.x; o[1] = (bf16)v.y; o[2] = (bf16)v.z; o[3] = (bf16)v.w;
    reinterpret_cast<bf16x4*>(out)[i] = o;
}

// ---------------- GEMM: C[M,N] = A[M,K] * B[N,K]^T  (row-major, K contig) ----------
// m97 structure + XOR-swizzled LDS chunks (swizzle on the global-address side).
template <typename OutT>
__global__ __launch_bounds__(256) void gemm_bt(const bf16* __restrict__ A,
                                               const bf16* __restrict__ B,
                                               OutT* __restrict__ C,
                                               int M, int N, int K, int ldc) {
    __shared__ bf16 As[128 * 32];
    __shared__ bf16 Bs[128 * 32];
    const int t    = threadIdx.x;
    const int wave = t >> 6, lane = t & 63;
    const int quad = lane >> 4, l15 = lane & 15;
    const int wm = (wave >> 1) * 64, wn = (wave & 1) * 64;
    const int bm = blockIdx.y * 128, bn = blockIdx.x * 128;

    f32x4 acc[4][4];
#pragma unroll
    for (int i = 0; i < 4; ++i)
#pragma unroll
        for (int j = 0; j < 4; ++j) acc[i][j] = (f32x4){0.f, 0.f, 0.f, 0.f};

    const int srow = t >> 2;
    const int scol = ((t & 3) ^ ((srow >> 1) & 3)) * 8;

    for (int k0 = 0; k0 < K; k0 += 32) {
        __syncthreads();
#pragma unroll
        for (int it = 0; it < 2; ++it) {
            gload16(A + (size_t)(bm + srow + it * 64) * K + k0 + scol,
                    As + it * 2048 + wave * 512);
            gload16(B + (size_t)(bn + srow + it * 64) * K + k0 + scol,
                    Bs + it * 2048 + wave * 512);
        }
        __syncthreads();

        bf16x8 af[4], bfb[4];
#pragma unroll
        for (int i = 0; i < 4; ++i) {
            const int r = wm + i * 16 + l15;
            af[i] = *reinterpret_cast<const bf16x8*>(&As[r * 32 + (quad ^ ((r >> 1) & 3)) * 8]);
        }
#pragma unroll
        for (int j = 0; j < 4; ++j) {
            const int r = wn + j * 16 + l15;
            bfb[j] = *reinterpret_cast<const bf16x8*>(&Bs[r * 32 + (quad ^ ((r >> 1) & 3)) * 8]);
        }
#pragma unroll
        for (int i = 0; i < 4; ++i)
#pragma unroll
            for (int j = 0; j < 4; ++j)
                acc[i][j] = __builtin_amdgcn_mfma_f32_16x16x32_bf16(af[i], bfb[j], acc[i][j], 0, 0, 0);
    }

#pragma unroll
    for (int i = 0; i < 4; ++i) {
        const int m0 = bm + wm + i * 16 + quad * 4;
#pragma unroll
        for (int j = 0; j < 4; ++j) {
            const int n = bn + wn + j * 16 + l15;
#pragma unroll
            for (int r = 0; r < 4; ++r)
                C[(size_t)(m0 + r) * ldc + n] = (OutT)acc[i][j][r];
        }
    }
}

// ---------------- RoPE, vectorized bf16x8: Q (32 heads) + K (8 heads) --------------
__global__ __launch_bounds__(320) void rope_kernel(bf16* __restrict__ qkv,
                                                   const float* __restrict__ cosT,
                                                   const float* __restrict__ sinT) {
    const int u    = threadIdx.x;
    const int row  = blockIdx.x;
    const int head = u >> 3, d0 = (u & 7) * 8;
    bf16* p = qkv + (size_t)row * QKV_N + head * 128 + d0;
    bf16x8 a = *reinterpret_cast<const bf16x8*>(p);
    bf16x8 b = *reinterpret_cast<const bf16x8*>(p + 64);
    const float4 c0 = *reinterpret_cast<const float4*>(cosT + row * 128 + d0);
    const float4 c1 = *reinterpret_cast<const float4*>(cosT + row * 128 + d0 + 4);
    const float4 s0 = *reinterpret_cast<const float4*>(sinT + row * 128 + d0);
    const float4 s1 = *reinterpret_cast<const float4*>(sinT + row * 128 + d0 + 4);
    float c[8] = {c0.x, c0.y, c0.z, c0.w, c1.x, c1.y, c1.z, c1.w};
    float s[8] = {s0.x, s0.y, s0.z, s0.w, s1.x, s1.y, s1.z, s1.w};
    bf16x8 oa, ob;
#pragma unroll
    for (int e = 0; e < 8; ++e) {
        const float x1 = (float)a[e], x2 = (float)b[e];
        oa[e] = (bf16)(x1 * c[e] - x2 * s[e]);
        ob[e] = (bf16)(x2 * c[e] + x1 * s[e]);
    }
    *reinterpret_cast<bf16x8*>(p)      = oa;
    *reinterpret_cast<bf16x8*>(p + 64) = ob;
}

// ---------------- K pack: fragment-order layout for coalesced flash loads ----------
// Kp[(kh*32+T)*16 + (j*4+kk)][lane=quad*16+l15][e] = K[T*64+j*16+l15][kh*128+kk*32+quad*8+e]
__global__ __launch_bounds__(256) void pack_k(const bf16* __restrict__ qkv,
                                              bf16* __restrict__ kp) {
    const int T  = blockIdx.x;     // kv tile 0..31
    const int kh = blockIdx.y;     // 0..7
    const int t  = threadIdx.x;
    bf16* outT = kp + ((size_t)kh * 32 + T) * 8192;
#pragma unroll
    for (int it = 0; it < 4; ++it) {
        const int u  = t + it * 256;
        const int ri = u >> 4;          // row in tile 0..63
        const int ci = u & 15;          // 8-elem chunk 0..15
        bf16x8 v = *reinterpret_cast<const bf16x8*>(
            qkv + (size_t)(T * 64 + ri) * QKV_N + K_OFF + kh * 128 + ci * 8);
        const int j = ri >> 4, l15 = ri & 15;
        const int kk = ci >> 2, quad = ci & 3;
        *reinterpret_cast<bf16x8*>(outT + ((size_t)(j * 4 + kk) * 64 + quad * 16 + l15) * 8) = v;
    }
}

// ---------------- V pack (transpose + fragment order) ------------------------------
// Vp[(kh*32+T)*16 + (dt*2+c)][lane][e] = V[T*64 + c*32+quad*8+e][kh*128 + dt*16+l15]
__global__ __launch_bounds__(256) void pack_v(const bf16* __restrict__ qkv,
                                              bf16* __restrict__ vp) {
    __shared__ bf16 T2[64][136];
    const int T  = blockIdx.x;
    const int kh = blockIdx.y;
    const int t  = threadIdx.x;
#pragma unroll
    for (int it = 0; it < 4; ++it) {
        const int u = t + it * 256;
        const int s = u >> 4, ci = u & 15;
        bf16x8 v = *reinterpret_cast<const bf16x8*>(
            qkv + (size_t)(T * 64 + s) * QKV_N + V_OFF + kh * 128 + ci * 8);
        *reinterpret_cast<bf16x8*>(&T2[s][ci * 8]) = v;
    }
    __syncthreads();
    bf16* outT = vp + ((size_t)kh * 32 + T) * 8192;
#pragma unroll
    for (int it = 0; it < 4; ++it) {
        const int u    = t + it * 256;     // frag-chunk 0..1023
        const int f    = u >> 6;           // dt*2+c
        const int lane = u & 63;
        const int dt = f >> 1, c = f & 1;
        const int quad = lane >> 4, l15 = lane & 15;
        bf16x8 o;
#pragma unroll
        for (int e = 0; e < 8; ++e)
            o[e] = T2[c * 32 + quad * 8 + e][dt * 16 + l15];
        *reinterpret_cast<bf16x8*>(outT + (size_t)u * 8) = o;
    }
}

// ---------------- flash attention: barrier-free + fully coalesced ------------------
// 256 thr = 4 waves, BQ=128. Wave w owns 16-row groups {w, 7-w} -> equal kv work per
// wave. K/V fragments are single contiguous 1KB wave-loads from the packed buffers
// (16 lines/load vs 64-line gathers of round 3). No staging LDS, no __syncthreads;
// LDS only for the per-wave P C->A-layout round trip.
__global__ __launch_bounds__(256, 2) void flash_attn(const bf16* __restrict__ qkv,
                                                     const bf16* __restrict__ kp,
                                                     const bf16* __restrict__ vp,
                                                     bf16* __restrict__ ctx) {
    const int blk   = blockIdx.x;
    const int idx   = blk >> 5;
    const int qtile = (idx < 8) ? (15 - idx) : (idx - 8);  // heavy blocks first
    const int h     = blk & 31;
    const int kh    = h >> 2;
    const int q0    = qtile * 128;
    const int t     = threadIdx.x;
    const int wave  = t >> 6, lane = t & 63;
    const int quad  = lane >> 4, l15 = lane & 15;

    __shared__ bf16 Ps[4 * 2 * 16 * 72];   // per-wave, per-group P tiles (18 KB)

    const bf16* Qb = qkv + h * HD;

    // balanced 16-row groups
    const int rb0 = wave * 16, rb1 = (7 - wave) * 16;
    const int e0  = q0 + rb0 + 16;   // causal kv bound, group 0
    const int e1  = q0 + rb1 + 16;   // causal kv bound, group 1 (>= e0)

    bf16x8 qf[2][4];
#pragma unroll
    for (int kk = 0; kk < 4; ++kk) {
        qf[0][kk] = *reinterpret_cast<const bf16x8*>(
            Qb + (size_t)(q0 + rb0 + l15) * QKV_N + kk * 32 + quad * 8);
        qf[1][kk] = *reinterpret_cast<const bf16x8*>(
            Qb + (size_t)(q0 + rb1 + l15) * QKV_N + kk * 32 + quad * 8);
    }

    float m_i[2][4], l_i[2][4];
    f32x4 o_acc[2][8];
#pragma unroll
    for (int g = 0; g < 2; ++g) {
#pragma unroll
        for (int r = 0; r < 4; ++r) { m_i[g][r] = -1e30f; l_i[g][r] = 0.f; }
#pragma unroll
        for (int dt = 0; dt < 8; ++dt) o_acc[g][dt] = (f32x4){0.f, 0.f, 0.f, 0.f};
    }

    const int crow0 = q0 + rb0 + quad * 4;   // C-layout row bases
    const int crow1 = q0 + rb1 + quad * 4;
    bf16* PsW[2] = {Ps + (wave * 2 + 0) * (16 * 72), Ps + (wave * 2 + 1) * (16 * 72)};

    for (int kv0 = 0; kv0 < e1; kv0 += 64) {
        const bool a0 = kv0 < e0;            // group 0 still active (wave-uniform)
        const size_t tb = ((size_t)kh * 32 + (kv0 >> 6)) * 1024;
        const bf16x8* KT = reinterpret_cast<const bf16x8*>(kp) + tb;
        const bf16x8* VT = reinterpret_cast<const bf16x8*>(vp) + tb;

        // ---- S = Q K^T; coalesced packed K fragments ----
        float sv0[4][4], sv1[4][4];
#pragma unroll
        for (int j = 0; j < 4; ++j) {
            f32x4 s0 = (f32x4){0.f, 0.f, 0.f, 0.f};
            f32x4 s1 = (f32x4){0.f, 0.f, 0.f, 0.f};
#pragma unroll
            for (int kk = 0; kk < 4; ++kk) {
                bf16x8 kf = KT[(j * 4 + kk) * 64 + lane];
                if (a0) s0 = __builtin_amdgcn_mfma_f32_16x16x32_bf16(qf[0][kk], kf, s0, 0, 0, 0);
                s1 = __builtin_amdgcn_mfma_f32_16x16x32_bf16(qf[1][kk], kf, s1, 0, 0, 0);
            }
            const int kvc = kv0 + j * 16 + l15;
            if (a0) {
                if (kv0 + 63 > q0 + rb0) {
#pragma unroll
                    for (int r = 0; r < 4; ++r)
                        sv0[j][r] = (kvc <= crow0 + r) ? s0[r] * ATT_SCALE : -1e30f;
                } else {
#pragma unroll
                    for (int r = 0; r < 4; ++r) sv0[j][r] = s0[r] * ATT_SCALE;
                }
            }
            if (kv0 + 63 > q0 + rb1) {
#pragma unroll
                for (int r = 0; r < 4; ++r)
                    sv1[j][r] = (kvc <= crow1 + r) ? s1[r] * ATT_SCALE : -1e30f;
            } else {
#pragma unroll
                for (int r = 0; r < 4; ++r) sv1[j][r] = s1[r] * ATT_SCALE;
            }
        }

        // ---- online softmax; P -> LDS (C-layout in, A-layout out) ----
        float al0[4], al1[4];
        if (a0) {
#pragma unroll
            for (int r = 0; r < 4; ++r) {
                float mt = fmaxf(fmaxf(sv0[0][r], sv0[1][r]), fmaxf(sv0[2][r], sv0[3][r]));
#pragma unroll
                for (int off = 1; off < 16; off <<= 1) mt = fmaxf(mt, __shfl_xor(mt, off));
                const float mn = fmaxf(m_i[0][r], mt);
                al0[r] = __expf(m_i[0][r] - mn);
                m_i[0][r] = mn;
                float rs = 0.f;
#pragma unroll
                for (int j = 0; j < 4; ++j) {
                    const float p = __expf(sv0[j][r] - mn);
                    rs += p;
                    PsW[0][(quad * 4 + r) * 72 + j * 16 + l15] = (bf16)p;
                }
#pragma unroll
                for (int off = 1; off < 16; off <<= 1) rs += __shfl_xor(rs, off);
                l_i[0][r] = l_i[0][r] * al0[r] + rs;
            }
        }
#pragma unroll
        for (int r = 0; r < 4; ++r) {
            float mt = fmaxf(fmaxf(sv1[0][r], sv1[1][r]), fmaxf(sv1[2][r], sv1[3][r]));
#pragma unroll
            for (int off = 1; off < 16; off <<= 1) mt = fmaxf(mt, __shfl_xor(mt, off));
            const float mn = fmaxf(m_i[1][r], mt);
            al1[r] = __expf(m_i[1][r] - mn);
            m_i[1][r] = mn;
            float rs = 0.f;
#pragma unroll
            for (int j = 0; j < 4; ++j) {
                const float p = __expf(sv1[j][r] - mn);
                rs += p;
                PsW[1][(quad * 4 + r) * 72 + j * 16 + l15] = (bf16)p;
            }
#pragma unroll
            for (int off = 1; off < 16; off <<= 1) rs += __shfl_xor(rs, off);
            l_i[1][r] = l_i[1][r] * al1[r] + rs;
        }

        // ---- rescale O accumulators ----
        if (a0) {
#pragma unroll
            for (int dt = 0; dt < 8; ++dt) {
                o_acc[0][dt][0] *= al0[0]; o_acc[0][dt][1] *= al0[1];
                o_acc[0][dt][2] *= al0[2]; o_acc[0][dt][3] *= al0[3];
            }
        }
#pragma unroll
        for (int dt = 0; dt < 8; ++dt) {
            o_acc[1][dt][0] *= al1[0]; o_acc[1][dt][1] *= al1[1];
            o_acc[1][dt][2] *= al1[2]; o_acc[1][dt][3] *= al1[3];
        }

        // ---- PV with coalesced packed V fragments ----
        bf16x8 pa0[2], pa1[2];
        if (a0) {
            pa0[0] = *reinterpret_cast<const bf16x8*>(&PsW[0][l15 * 72 + quad * 8]);
            pa0[1] = *reinterpret_cast<const bf16x8*>(&PsW[0][l15 * 72 + 32 + quad * 8]);
        }
        pa1[0] = *reinterpret_cast<const bf16x8*>(&PsW[1][l15 * 72 + quad * 8]);
        pa1[1] = *reinterpret_cast<const bf16x8*>(&PsW[1][l15 * 72 + 32 + quad * 8]);
#pragma unroll
        for (int dt = 0; dt < 8; ++dt) {
#pragma unroll
            for (int c = 0; c < 2; ++c) {
                bf16x8 vb = VT[(dt * 2 + c) * 64 + lane];
                if (a0) o_acc[0][dt] = __builtin_amdgcn_mfma_f32_16x16x32_bf16(pa0[c], vb, o_acc[0][dt], 0, 0, 0);
                o_acc[1][dt] = __builtin_amdgcn_mfma_f32_16x16x32_bf16(pa1[c], vb, o_acc[1][dt], 0, 0, 0);
            }
        }
    }

    // ---- epilogue ----
#pragma unroll
    for (int dt = 0; dt < 8; ++dt)
#pragma unroll
        for (int r = 0; r < 4; ++r) {
            ctx[(size_t)(crow0 + r) * DMODEL + h * HD + dt * 16 + l15] =
                (bf16)(o_acc[0][dt][r] / l_i[0][r]);
            ctx[(size_t)(crow1 + r) * DMODEL + h * HD + dt * 16 + l15] =
                (bf16)(o_acc[1][dt][r] / l_i[1][r]);
        }
}

// ---------------- launch ----------------
extern "C" void kernel_launch(void* const* d_in, const int* in_sizes, int n_in,
                              void* d_out, int out_size, void* d_ws, size_t ws_size,
                              hipStream_t stream) {
    const float* x    = (const float*)d_in[0];
    const float* cosT = (const float*)d_in[1];
    const float* sinT = (const float*)d_in[2];
    const float* Wq   = (const float*)d_in[3];
    const float* Wk   = (const float*)d_in[4];
    const float* Wv   = (const float*)d_in[5];
    const float* Wo   = (const float*)d_in[6];
    float* out = (float*)d_out;

    // workspace (bf16 elems): xb | Wqkv | Wo | QKV | ctx ; Kp/Vp alias xb (dead
    // after the QKV GEMM, and pack runs after RoPE which is after the GEMM).
    bf16* xb   = (bf16*)d_ws;
    bf16* Wqkv = xb   + (size_t)S_LEN * DMODEL;        // 6144 x 4096
    bf16* Wob  = Wqkv + (size_t)QKV_N * DMODEL;        // 4096 x 4096
    bf16* QKV  = Wob  + (size_t)DMODEL * DMODEL;       // 2048 x 6144
    bf16* ctx  = QKV  + (size_t)S_LEN * QKV_N;         // 2048 x 4096
    bf16* Kp   = xb;                                   // 8 x 32 x 8192 = 2M elems
    bf16* Vp   = xb + (size_t)2 * 1024 * 1024;         // 2M elems

    cast_f32_bf16<<<(S_LEN * DMODEL / 4 + 255) / 256, 256, 0, stream>>>(x, xb, S_LEN * DMODEL / 4);
    cast_f32_bf16<<<(DMODEL * DMODEL / 4 + 255) / 256, 256, 0, stream>>>(Wq, Wqkv, DMODEL * DMODEL / 4);
    cast_f32_bf16<<<(1024 * DMODEL / 4 + 255) / 256, 256, 0, stream>>>(
        Wk, Wqkv + (size_t)4096 * DMODEL, 1024 * DMODEL / 4);
    cast_f32_bf16<<<(1024 * DMODEL / 4 + 255) / 256, 256, 0, stream>>>(
        Wv, Wqkv + (size_t)5120 * DMODEL, 1024 * DMODEL / 4);
    cast_f32_bf16<<<(DMODEL * DMODEL / 4 + 255) / 256, 256, 0, stream>>>(Wo, Wob, DMODEL * DMODEL / 4);

    // fused QKV projection: (2048 x 4096) @ (6144 x 4096)^T -> 2048 x 6144 bf16
    gemm_bt<bf16><<<dim3(QKV_N / 128, S_LEN / 128), 256, 0, stream>>>(
        xb, Wqkv, QKV, S_LEN, QKV_N, DMODEL, QKV_N);

    // RoPE on Q and K (xb is dead from here on)
    rope_kernel<<<dim3(S_LEN), 320, 0, stream>>>(QKV, cosT, sinT);

    // pack K and V into MFMA-fragment order (coalesced flash loads)
    pack_k<<<dim3(32, 8), 256, 0, stream>>>(QKV, Kp);
    pack_v<<<dim3(32, 8), 256, 0, stream>>>(QKV, Vp);

    // flash attention -> ctx bf16; barrier-free, balanced, coalesced
    flash_attn<<<dim3(16 * 32), 256, 0, stream>>>(QKV, Kp, Vp, ctx);

    // output projection: (2048 x 4096) @ (4096 x 4096)^T -> fp32 out
    gemm_bt<float><<<dim3(DMODEL / 128, S_LEN / 128), 256, 0, stream>>>(
        ctx, Wob, out, S_LEN, DMODEL, DMODEL, DMODEL);
}